// Round 3
// baseline (221.806 us; speedup 1.0000x reference)
//
#include <hip/hip_runtime.h>
#include <hip/hip_bf16.h>

#define NROWS 8192
#define DIM   1024
#define OUTD  1024
#define NE    16
#define BM    128
#define BN    128
#define BK    32
#define MAXT  96
#define NKSTEP (DIM / BK)   // 32
#define NTILE  (OUTD / BN)  // 8

typedef short s16x8 __attribute__((ext_vector_type(8)));
typedef float f32x4 __attribute__((ext_vector_type(4)));

__device__ __forceinline__ unsigned f2bf(float f) {
  __hip_bfloat16 h = __float2bfloat16(f);
  return (unsigned)__builtin_bit_cast(unsigned short, h);
}

__device__ __forceinline__ void gload_lds16(const void* g, void* l) {
  __builtin_amdgcn_global_load_lds(
      (const __attribute__((address_space(1))) void*)g,
      (__attribute__((address_space(3))) void*)l, 16, 0, 0);
}

// ---------------- init: zero counts[16] + cursors[16] ----------------
__global__ void init_kernel(int* counts) {
  int t = threadIdx.x;
  if (t < 32) counts[t] = 0;
}

// ---------------- We fp32 -> bf16 ----------------
__global__ __launch_bounds__(256) void convert_we_kernel(
    const float* __restrict__ W, ushort* __restrict__ o) {
  size_t i = ((size_t)blockIdx.x * 256 + threadIdx.x) * 8;
  float4 a = *(const float4*)(W + i);
  float4 b = *(const float4*)(W + i + 4);
  unsigned w0 = f2bf(a.x) | (f2bf(a.y) << 16);
  unsigned w1 = f2bf(a.z) | (f2bf(a.w) << 16);
  unsigned w2 = f2bf(b.x) | (f2bf(b.y) << 16);
  unsigned w3 = f2bf(b.z) | (f2bf(b.w) << 16);
  *(uint4*)(o + i) = make_uint4(w0, w1, w2, w3);
}

// ------- gate: full-D fp32 logits (Wg in LDS), butterfly reduce, softmax,
// ------- argmax, fused x->bf16 conversion + fused expert histogram -------
// 512 blocks x 256 thr; wave w handles rows n0+4w .. n0+4w+3 jointly.
// lane covers cols {j*256 + 4*lane .. +3 : j=0..3}.
__global__ __launch_bounds__(256) void gate_kernel(
    const float* __restrict__ x, const float* __restrict__ Wg,
    float* __restrict__ gate_out, int* __restrict__ eid,
    float* __restrict__ wsel, ushort* __restrict__ xb,
    int* __restrict__ counts)
{
  __shared__ __align__(16) float4 wg4[NE * 256];  // 64 KB fp32 Wg
  __shared__ int hist[NE];
  int t = threadIdx.x, wid = t >> 6, lane = t & 63;
  if (t < NE) hist[t] = 0;
  const float4* wgg = (const float4*)Wg;
  #pragma unroll
  for (int i = 0; i < 16; ++i) wg4[t + i * 256] = wgg[t + i * 256];
  __syncthreads();

  int n0 = blockIdx.x * 16 + wid * 4;

  float acc[4][NE];
  #pragma unroll
  for (int r = 0; r < 4; ++r)
    #pragma unroll
    for (int e = 0; e < NE; ++e) acc[r][e] = 0.f;

  #pragma unroll
  for (int j = 0; j < 4; ++j) {
    float4 xv[4];
    #pragma unroll
    for (int r = 0; r < 4; ++r) {
      xv[r] = *(const float4*)(x + (size_t)(n0 + r) * DIM + j * 256 + 4 * lane);
      unsigned lo = f2bf(xv[r].x) | (f2bf(xv[r].y) << 16);
      unsigned hi = f2bf(xv[r].z) | (f2bf(xv[r].w) << 16);
      *(uint2*)(xb + (size_t)(n0 + r) * DIM + j * 256 + 4 * lane) = make_uint2(lo, hi);
    }
    #pragma unroll
    for (int e = 0; e < NE; ++e) {
      float4 w = wg4[e * 256 + j * 64 + lane];
      #pragma unroll
      for (int r = 0; r < 4; ++r)
        acc[r][e] += xv[r].x * w.x + xv[r].y * w.y + xv[r].z * w.z + xv[r].w * w.w;
    }
  }

  #pragma unroll
  for (int r = 0; r < 4; ++r) {
    int n = n0 + r;
    float v[NE];
    #pragma unroll
    for (int e = 0; e < NE; ++e) v[e] = acc[r][e];
    // 16 distributed sums -> 1 per lane (expert = f(lane bits 2..5)): 17 shfl
    #pragma unroll
    for (int i = 0; i < 8; ++i) {
      float send = (lane & 32) ? v[i] : v[i + 8];
      float recv = __shfl_xor(send, 32, 64);
      v[i] = ((lane & 32) ? v[i + 8] : v[i]) + recv;
    }
    #pragma unroll
    for (int i = 0; i < 4; ++i) {
      float send = (lane & 16) ? v[i] : v[i + 4];
      float recv = __shfl_xor(send, 16, 64);
      v[i] = ((lane & 16) ? v[i + 4] : v[i]) + recv;
    }
    #pragma unroll
    for (int i = 0; i < 2; ++i) {
      float send = (lane & 8) ? v[i] : v[i + 2];
      float recv = __shfl_xor(send, 8, 64);
      v[i] = ((lane & 8) ? v[i + 2] : v[i]) + recv;
    }
    {
      float send = (lane & 4) ? v[0] : v[1];
      float recv = __shfl_xor(send, 4, 64);
      v[0] = ((lane & 4) ? v[1] : v[0]) + recv;
    }
    v[0] += __shfl_xor(v[0], 2, 64);
    v[0] += __shfl_xor(v[0], 1, 64);
    float lg = v[0];
    int e = ((lane >> 5) & 1) * 8 + ((lane >> 4) & 1) * 4 +
            ((lane >> 3) & 1) * 2 + ((lane >> 2) & 1);
    float m = lg;
    m = fmaxf(m, __shfl_xor(m, 4, 64));
    m = fmaxf(m, __shfl_xor(m, 8, 64));
    m = fmaxf(m, __shfl_xor(m, 16, 64));
    m = fmaxf(m, __shfl_xor(m, 32, 64));
    float p = expf(lg - m);
    float s = p;
    s += __shfl_xor(s, 4, 64);
    s += __shfl_xor(s, 8, 64);
    s += __shfl_xor(s, 16, 64);
    s += __shfl_xor(s, 32, 64);
    float inv = 1.f / s;
    if ((lane & 3) == 0) gate_out[(size_t)n * NE + e] = p * inv;
    unsigned long long msk = __ballot(lg == m);
    if (lane == 0) {
      int fl = __builtin_ctzll(msk);
      int ebest = ((fl >> 5) & 1) * 8 + ((fl >> 4) & 1) * 4 +
                  ((fl >> 3) & 1) * 2 + ((fl >> 2) & 1);
      eid[n] = ebest;
      wsel[n] = inv;  // max weight = exp(0)/sum
      atomicAdd(&hist[ebest], 1);
    }
  }
  __syncthreads();
  if (t < NE && hist[t]) atomicAdd(&counts[t], hist[t]);
}

// ---------------- plan: one wave, shfl prefix sums ----------------
__global__ void plan_kernel(const int* __restrict__ counts,
                            int* __restrict__ offsets, int4* __restrict__ tiles)
{
  int lane = threadIdx.x;  // 64 threads
  int c = (lane < NE) ? counts[lane] : 0;
  int nt = (c + BM - 1) >> 7;
  int po = c, pt = nt;
  #pragma unroll
  for (int d = 1; d < 16; d <<= 1) {
    int oc = __shfl_up(po, d, 64);
    int ot = __shfl_up(pt, d, 64);
    if (lane >= d) { po += oc; pt += ot; }
  }
  int off = po - c;
  int tbase = pt - nt;
  if (lane < NE) offsets[lane] = off;
  if (lane == NE - 1) offsets[NE] = po;
  int total_t = __shfl(pt, NE - 1, 64);
  if (lane < NE) {
    int ti = 0;
    for (int m = 0; m < c; m += BM, ++ti)
      tiles[tbase + ti] = make_int4(lane, off + m, (c - m < BM) ? (c - m) : BM, 0);
  }
  for (int i = total_t + lane; i < MAXT; i += 64)
    tiles[i] = make_int4(-1, 0, 0, 0);
}

// ---------------- scatter rows by expert ----------------
__global__ __launch_bounds__(256) void scatter_kernel(
    const int* __restrict__ eid, const int* __restrict__ offsets,
    int* __restrict__ cursors, int* __restrict__ rowids)
{
  __shared__ int h[NE];
  __shared__ int base[NE];
  int t = threadIdx.x;
  if (t < NE) h[t] = 0;
  __syncthreads();
  int n = blockIdx.x * 256 + t;
  int e = eid[n];
  int local = atomicAdd(&h[e], 1);
  __syncthreads();
  if (t < NE) base[t] = h[t] ? atomicAdd(&cursors[t], h[t]) : 0;
  __syncthreads();
  rowids[offsets[e] + base[e] + local] = n;
}

// ------- gathered per-expert GEMM, bf16 inputs, global_load_lds staging -------
// LDS layout per tile: row-major rows of 64B (BK=32 bf16), slot-swizzled:
// phys slot = logical cg ^ ((row>>1)&3). DMA writes linearly (lane*16), the
// source address is pre-swizzled; ds_read applies the same XOR -> 2-way max.
__global__ __launch_bounds__(256) void moe_gemm_kernel(
    const ushort* __restrict__ xb, const ushort* __restrict__ Web,
    const float* __restrict__ be, const int* __restrict__ rowids,
    const float* __restrict__ wsel, const int4* __restrict__ tiles,
    float* __restrict__ out)
{
  __shared__ __align__(16) char lds[32768];  // A0 A1 | B0 B1, 8KB each
  __shared__ int   rows_s[BM];
  __shared__ float w_s[BM];

  int4 ti = tiles[blockIdx.x];
  int e = ti.x;
  if (e < 0) return;
  int srow = ti.y, nvalid = ti.z;
  int t = threadIdx.x, lane = t & 63;
  int wid = t >> 6, wm = wid >> 1, wn = wid & 1;
  int ncol0 = blockIdx.y * BN;

  if (t < BM) {
    int valid = t < nvalid;
    int rid = valid ? rowids[srow + t] : 0;
    rows_s[t] = valid ? rid : -1;
    w_s[t] = valid ? wsel[rid] : 0.f;
  }

  // staging geometry: thread t -> row r1=t>>2 (and r1+64), phys slot t&3
  int r1 = t >> 2, sl = t & 3;
  int r2 = r1 + 64;
  int cg = sl ^ ((r1 >> 1) & 3);   // same for r2 ((row+64)>>1 keeps &3)
  int rida1 = (r1 < nvalid) ? rowids[srow + r1] : 0;
  int rida2 = (r2 < nvalid) ? rowids[srow + r2] : 0;
  const ushort* ap1 = xb + (size_t)rida1 * DIM + cg * 8;
  const ushort* ap2 = xb + (size_t)rida2 * DIM + cg * 8;
  const ushort* bb  = Web + (size_t)e * OUTD * DIM + (size_t)ncol0 * DIM + cg * 8;
  const ushort* bp1 = bb + (size_t)r1 * DIM;
  const ushort* bp2 = bb + (size_t)r2 * DIM;

  f32x4 zero = {0.f, 0.f, 0.f, 0.f};
  f32x4 acc[4][4];
  #pragma unroll
  for (int i = 0; i < 4; ++i)
    #pragma unroll
    for (int j = 0; j < 4; ++j) acc[i][j] = zero;

  auto stage = [&](int b, int koff) {
    char* A = lds + b * 8192;
    char* B = lds + 16384 + b * 8192;
    gload_lds16(ap1 + koff, A + t * 16);
    gload_lds16(ap2 + koff, A + 4096 + t * 16);
    gload_lds16(bp1 + koff, B + t * 16);
    gload_lds16(bp2 + koff, B + 4096 + t * 16);
  };
  stage(0, 0);

  unsigned rl15 = lane & 15, rcg = lane >> 4;
  for (int ks = 0; ks < NKSTEP; ++ks) {
    __syncthreads();  // drains vmcnt: current buffer staged, prev reads done
    if (ks + 1 < NKSTEP) stage((ks + 1) & 1, (ks + 1) * BK);
    const char* A = lds + (ks & 1) * 8192;
    const char* B = lds + 16384 + (ks & 1) * 8192;
    s16x8 af[4], bf_[4];
    #pragma unroll
    for (int f = 0; f < 4; ++f) {
      unsigned rA = wm * 64 + f * 16 + rl15;
      af[f] = *(const s16x8*)(A + rA * 64 + ((rcg ^ ((rA >> 1) & 3)) * 16));
      unsigned rB = wn * 64 + f * 16 + rl15;
      bf_[f] = *(const s16x8*)(B + rB * 64 + ((rcg ^ ((rB >> 1) & 3)) * 16));
    }
    #pragma unroll
    for (int fm = 0; fm < 4; ++fm)
      #pragma unroll
      for (int fn = 0; fn < 4; ++fn)
        acc[fm][fn] = __builtin_amdgcn_mfma_f32_16x16x32_bf16(af[fm], bf_[fn], acc[fm][fn], 0, 0, 0);
  }

  // epilogue: out[row][col] = w * (acc + be[e][col])
  int rgrp = lane >> 4;
  #pragma unroll
  for (int fn = 0; fn < 4; ++fn) {
    int col = ncol0 + wn * 64 + fn * 16 + (lane & 15);
    float bev = be[e * OUTD + col];
    #pragma unroll
    for (int fm = 0; fm < 4; ++fm) {
      #pragma unroll
      for (int j = 0; j < 4; ++j) {
        int rl = wm * 64 + fm * 16 + rgrp * 4 + j;
        int orow = rows_s[rl];
        if (orow >= 0) {
          float w = w_s[rl];
          out[(size_t)orow * OUTD + col] = w * (acc[fm][fn][j] + bev);
        }
      }
    }
  }
}

extern "C" void kernel_launch(void* const* d_in, const int* in_sizes, int n_in,
                              void* d_out, int out_size, void* d_ws, size_t ws_size,
                              hipStream_t stream) {
  const float* x  = (const float*)d_in[0];
  const float* Wg = (const float*)d_in[1];
  const float* We = (const float*)d_in[2];
  const float* be = (const float*)d_in[3];
  float* out = (float*)d_out;
  float* gate_out = out + (size_t)NROWS * OUTD;

  char* ws = (char*)d_ws;
  int*  counts  = (int*)ws;                        // 16 @ 0
  int*  cursors = counts + 16;                     // 16 @ 64
  int*  offsets = counts + 32;                     // 17 @ 128
  int4* tiles   = (int4*)(ws + 256);               // MAXT*16 B
  int*  eidp    = (int*)(ws + 4096);               // 32 KB
  float* wselp  = (float*)(ws + 4096 + 4 * NROWS); // 32 KB
  int*  rowids  = (int*)(ws + 4096 + 8 * NROWS);   // 32 KB
  ushort* xb    = (ushort*)(ws + (1u << 20));                  // 16 MB
  ushort* Web   = (ushort*)(ws + (1u << 20) + 16777216u);      // 32 MB

  hipLaunchKernelGGL(init_kernel, dim3(1), dim3(64), 0, stream, counts);
  hipLaunchKernelGGL(convert_we_kernel, dim3(8192), dim3(256), 0, stream, We, Web);
  hipLaunchKernelGGL(gate_kernel, dim3(NROWS / 16), dim3(256), 0, stream,
                     x, Wg, gate_out, eidp, wselp, xb, counts);
  hipLaunchKernelGGL(plan_kernel, dim3(1), dim3(64), 0, stream, counts, offsets, tiles);
  hipLaunchKernelGGL(scatter_kernel, dim3(NROWS / 256), dim3(256), 0, stream,
                     eidp, offsets, cursors, rowids);
  hipLaunchKernelGGL(moe_gemm_kernel, dim3(MAXT, NTILE), dim3(256), 0, stream,
                     xb, Web, be, rowids, wselp, tiles, out);
}